// Round 4
// baseline (65.835 us; speedup 1.0000x reference)
//
#include <hip/hip_runtime.h>
#include <stdint.h>

typedef unsigned long long u64;
typedef unsigned int u32;
typedef unsigned short u16;
typedef unsigned char u8;

#define Bn 32
#define Nn 320
#define WPN 5                   // u64 words per 320-bit adjacency row
#define MAXD 10
#define NH 8
#define ESTR 12                 // emb_s row stride in floats
#define NCH 5                   // 64-source chunks per graph
#define TPB 128                 // 2 waves per chunk
#define POOL 12288              // padded-CSR u16 entry pool (24.6 KB)
#define DUMMY Nn                // pad index -> S[DUMMY] == 0 always

// ---------------------------------------------------------------------------
// Input-format sniffing: bool arrays may arrive as 1 byte or 4 bytes/element.
// ---------------------------------------------------------------------------
__device__ __forceinline__ bool detect_byte_mode(const u32* a32) {
    int lane = threadIdx.x & 63;
    u32 or0 = 0, or1 = 0;
    #pragma unroll
    for (int k = 0; k < 16; ++k) {
        u32 v = a32[lane + k * 64];
        or0 |= v & 0x000000FFu;
        or1 |= v & 0x0000FF00u;
    }
    bool a0 = __any(or0 != 0);
    bool a1 = __any(or1 != 0);
    return a0 && a1;
}

// pack one adjacency row (node v) into 5 u64 words, masked to nn
__device__ __forceinline__ void pack_row(const u8* a8, bool bytemode, int b,
                                         int nn, int v, u64 (&ar)[WPN]) {
    #pragma unroll
    for (int w = 0; w < WPN; ++w) ar[w] = 0ull;
    if (v >= nn) return;
    if (bytemode) {
        const uint4* p = (const uint4*)(a8 + (size_t)(b * Nn + v) * Nn);
        #pragma unroll
        for (int w = 0; w < WPN; ++w) {
            u64 bits = 0;
            #pragma unroll
            for (int q = 0; q < 4; ++q) {
                uint4 x = p[w * 4 + q];
                u32 n0 = ((x.x & 0x01010101u) * 0x01020408u) >> 24;
                u32 n1 = ((x.y & 0x01010101u) * 0x01020408u) >> 24;
                u32 n2 = ((x.z & 0x01010101u) * 0x01020408u) >> 24;
                u32 n3 = ((x.w & 0x01010101u) * 0x01020408u) >> 24;
                u64 nib = (u64)((n0 & 0xF) | ((n1 & 0xF) << 4) |
                                ((n2 & 0xF) << 8) | ((n3 & 0xF) << 12));
                bits |= nib << (q * 16);
            }
            ar[w] = bits;
        }
    } else {
        const uint4* p = (const uint4*)(((const u32*)a8) + (size_t)(b * Nn + v) * Nn);
        #pragma unroll
        for (int w = 0; w < WPN; ++w) {
            u64 bits = 0;
            #pragma unroll
            for (int q = 0; q < 16; ++q) {
                uint4 x = p[w * 16 + q];
                u64 nib = (u64)((x.x != 0u) | ((x.y != 0u) << 1) |
                                ((x.z != 0u) << 2) | ((x.w != 0u) << 3));
                bits |= nib << (q * 4);
            }
            ar[w] = bits;
        }
    }
    #pragma unroll
    for (int w = 0; w < WPN; ++w) {
        int cc = nn - w * 64;
        u64 msk = (cc >= 64) ? ~0ull : ((cc <= 0) ? 0ull : ((1ull << cc) - 1ull));
        ar[w] &= msk;
    }
}

__device__ __forceinline__ int row_degree(const u64 (&ar)[WPN]) {
    int d = 0;
    #pragma unroll
    for (int w = 0; w < WPN; ++w) d += __popcll(ar[w]);
    return d;
}

// ---------------------------------------------------------------------------
// Kernel 1: padded-CSR node-centric multi-source BFS (64 sources per block).
// 160 blocks (graph x 64-src chunk) x 128 threads; thread owns nodes
// v = t, t+128, t+256(<320). Per level, per node: ceil(deg/8) iterations of
// {1 ds_read_b128 index load + 8 pipelined ds_read_b64 S-gathers} — no
// address-dependent chains, ctz extraction paid once at CSR build.
// ---------------------------------------------------------------------------
__global__ __launch_bounds__(TPB) void wave_bfs(
        const u8* __restrict__ a8,
        const int* __restrict__ nn_,
        u8* __restrict__ idxg) {
    bool bytemode = detect_byte_mode((const u32*)a8);
    int blk = blockIdx.x;
    int b = blk / NCH;
    int c = blk % NCH;
    int t = threadIdx.x;
    int nn = nn_[b];
    int base = c * 64;

    __shared__ __align__(16) u16 csr[POOL];        // 24576 B
    __shared__ u16 off[Nn];                        // 640 B (exclusive offsets)
    __shared__ u16 szs[Nn];                        // 640 B (padded sizes)
    __shared__ u64 S[2][Nn + 8];                   // 5248 B (+dummy slots)
    __shared__ __align__(16) u8 idx_s[64][Nn];     // 20480 B

    // zero idx tile: 5120 u32 / 128 threads = 40 each
    #pragma unroll
    for (int i = 0; i < 40; ++i) ((u32*)idx_s)[i * TPB + t] = 0;
    if (t < 8) { S[0][Nn + t] = 0ull; S[1][Nn + t] = 0ull; }

    // ---- pack rows into registers; init S[0], degree sizes ----
    u64 ar0[WPN], ar1[WPN], ar2[WPN];
    pack_row(a8, bytemode, b, nn, t,       ar0);
    pack_row(a8, bytemode, b, nn, t + 128, ar1);
    if (t < 64) pack_row(a8, bytemode, b, nn, t + 256, ar2);

    szs[t]       = (u16)((row_degree(ar0) + 7) & ~7);
    szs[t + 128] = (u16)((row_degree(ar1) + 7) & ~7);
    if (t < 64) szs[t + 256] = (u16)((row_degree(ar2) + 7) & ~7);

    {   // S[0] init: source nodes get their own bit
        int v0 = t, v1 = t + 128, v2 = t + 256;
        S[0][v0] = (v0 >= base && v0 < base + 64 && v0 < nn) ? (1ull << (v0 - base)) : 0ull;
        S[0][v1] = (v1 >= base && v1 < base + 64 && v1 < nn) ? (1ull << (v1 - base)) : 0ull;
        if (t < 64)
            S[0][v2] = (v2 >= base && v2 < base + 64 && v2 < nn) ? (1ull << (v2 - base)) : 0ull;
    }
    __syncthreads();

    // diag distances (after idx zeroing is barrier-complete)
    {
        int v0 = t, v1 = t + 128, v2 = t + 256;
        if (v0 >= base && v0 < base + 64 && v0 < nn) idx_s[v0 - base][v0] = 1;
        if (v1 >= base && v1 < base + 64 && v1 < nn) idx_s[v1 - base][v1] = 1;
        if (t < 64 && v2 >= base && v2 < base + 64 && v2 < nn) idx_s[v2 - base][v2] = 1;
    }

    // ---- exclusive prefix scan of padded sizes (wave 0 only) ----
    if (t < 64) {
        int lane = t;
        u32 carry = 0;
        for (int seg = 0; seg < 5; ++seg) {
            int v = seg * 64 + lane;
            u32 s0 = szs[v];
            u32 x = s0;
            #pragma unroll
            for (int d = 1; d < 64; d <<= 1) {
                u32 y = (u32)__shfl_up((int)x, d, 64);
                if (lane >= d) x += y;
            }
            off[v] = (u16)(carry + x - s0);
            carry += (u32)__shfl((int)x, 63, 64);
        }
    }
    __syncthreads();

    // ---- fill CSR (ctz extraction, once) ----
    {
        #define FILL_CSR(V, AR)                                               \
        do {                                                                  \
            int o = off[V]; int pe = o + szs[V];                              \
            if (pe > POOL) { szs[V] = 0; break; }                             \
            for (int w = 0; w < WPN; ++w) {                                   \
                u64 m = AR[w]; int ub = w * 64;                               \
                while (m) { csr[o++] = (u16)(ub + (int)__builtin_ctzll(m));   \
                            m &= m - 1; }                                     \
            }                                                                 \
            while (o < pe) csr[o++] = DUMMY;                                  \
        } while (0)
        FILL_CSR(t, ar0);
        FILL_CSR(t + 128, ar1);
        if (t < 64) FILL_CSR(t + 256, ar2);
        #undef FILL_CSR
    }

    int vs = nn - base; if (vs > 64) vs = 64; if (vs < 0) vs = 0;
    u64 full = (vs >= 64) ? ~0ull : ((1ull << vs) - 1ull);
    __syncthreads();

    // ---- level-synchronous BFS ----
    int p = 0;
    for (int level = 1; level <= Nn; ++level) {
        const u64* Sp = S[p];
        u64* Sn = S[p ^ 1];
        u8 val = (u8)((level < MAXD ? level : MAXD) + 1);
        int changed = 0;

        #define NODE_STEP(V)                                                  \
        do {                                                                  \
            u64 mo = Sp[V]; u64 acc = mo;                                     \
            if (mo != full) {                                                 \
                int o = off[V], e = o + szs[V];                               \
                for (; o < e; o += 8) {                                       \
                    uint4 w4 = *(const uint4*)(csr + o);                      \
                    int i0 = w4.x & 0xFFFF, i1 = (int)(w4.x >> 16);           \
                    int i2 = w4.y & 0xFFFF, i3 = (int)(w4.y >> 16);           \
                    int i4 = w4.z & 0xFFFF, i5 = (int)(w4.z >> 16);           \
                    int i6 = w4.w & 0xFFFF, i7 = (int)(w4.w >> 16);           \
                    u64 g0 = Sp[i0], g1 = Sp[i1], g2 = Sp[i2], g3 = Sp[i3];   \
                    u64 g4 = Sp[i4], g5 = Sp[i5], g6 = Sp[i6], g7 = Sp[i7];   \
                    acc |= ((g0 | g1) | (g2 | g3)) | ((g4 | g5) | (g6 | g7)); \
                }                                                             \
            }                                                                 \
            Sn[V] = acc;                                                      \
            u64 nw = acc & ~mo;                                               \
            if (nw) {                                                         \
                changed = 1;                                                  \
                do { int s2 = (int)__builtin_ctzll(nw); nw &= nw - 1;         \
                     idx_s[s2][V] = val; } while (nw);                        \
            }                                                                 \
        } while (0)

        NODE_STEP(t);
        NODE_STEP(t + 128);
        if (t < 64) NODE_STEP(t + 256);
        #undef NODE_STEP

        if (__syncthreads_count(changed) == 0) break;
        p ^= 1;
    }

    // ---- writeout: 64 rows x 320 B = 1280 uint4, coalesced ----
    {
        uint4* dst = (uint4*)(idxg + ((size_t)b * Nn + base) * Nn);
        const uint4* src = (const uint4*)idx_s;
        #pragma unroll
        for (int i = 0; i < 10; ++i) dst[i * TPB + t] = src[i * TPB + t];
    }
}

// ---------------------------------------------------------------------------
// Kernel 2: pure bandwidth gather-write. 2560 blocks x 256 threads x 10 f4.
// ---------------------------------------------------------------------------
#define K3_TPB 256
#define K3_PER 10
#define K3_BLOCKS ((Bn * Nn * Nn * (NH / 4)) / (K3_TPB * K3_PER))   // 2560

__global__ __launch_bounds__(K3_TPB) void emb_write(
        const u8* __restrict__ idxg,
        const float* __restrict__ emb,
        float4* __restrict__ out4) {
    __shared__ __align__(16) float emb_s[(MAXD + 2) * ESTR];   // 576 B
    int t = threadIdx.x;
    if (t < (MAXD + 2) * NH) emb_s[(t >> 3) * ESTR + (t & 7)] = emb[t];
    __syncthreads();
    size_t base = (size_t)blockIdx.x * (K3_TPB * K3_PER);
    #pragma unroll
    for (int i = 0; i < K3_PER; ++i) {
        size_t G = base + (size_t)(i * K3_TPB + t);
        int e = idxg[G >> 1];
        out4[G] = *(const float4*)(emb_s + e * ESTR + ((t & 1) << 2));
    }
}

extern "C" void kernel_launch(void* const* d_in, const int* in_sizes, int n_in,
                              void* d_out, int out_size, void* d_ws, size_t ws_size,
                              hipStream_t stream) {
    const u8*    adj = (const u8*)d_in[0];
    const int*   nn  = (const int*)d_in[1];
    const float* emb = (const float*)d_in[2];

    u8* idxg = (u8*)d_ws;   // 3.28 MB dist-index intermediate

    wave_bfs<<<Bn * NCH, TPB, 0, stream>>>(adj, nn, idxg);
    emb_write<<<K3_BLOCKS, K3_TPB, 0, stream>>>(idxg, emb, (float4*)d_out);
}

// Round 5
// 30.087 us; speedup vs baseline: 2.1882x; 2.1882x over previous
//
#include <hip/hip_runtime.h>
#include <stdint.h>

typedef unsigned long long u64;
typedef unsigned int u32;
typedef unsigned char u8;

#define Bn 32
#define Nn 320
#define WPN 5                 // 64-bit words per 320-bit row
#define ROWW 6                // padded row stride in u64 (48 B)
#define MAXD 10
#define NH 8
#define ADJP_WORDS (Bn * Nn * ROWW)   // 61440 u64 (padded row-major)
#define CH 16                 // sources per block (4 per wave)
#define NCHUNK (Nn / CH)      // 20
#define TPB 256               // four waves per block
#define ESTR 12               // emb_s row stride in floats
#define IDXSTR 336            // idx_s row stride in bytes
#define MASK20 ((1u << 20) - 1u)

// 16-lane (DPP row) OR-reduce step: VALU only, no DS-pipe traffic.
template<int CTRL> __device__ __forceinline__ u64 ror_or64(u64 v) {
    u32 lo = (u32)v, hi = (u32)(v >> 32);
    lo |= (u32)__builtin_amdgcn_update_dpp(0, (int)lo, CTRL, 0xF, 0xF, true);
    hi |= (u32)__builtin_amdgcn_update_dpp(0, (int)hi, CTRL, 0xF, 0xF, true);
    return ((u64)hi << 32) | lo;
}
template<int CTRL> __device__ __forceinline__ int ror_add(int v) {
    return v + __builtin_amdgcn_update_dpp(0, v, CTRL, 0xF, 0xF, true);
}
#define ROW_ROR_1 0x121
#define ROW_ROR_2 0x122
#define ROW_ROR_4 0x124
#define ROW_ROR_8 0x128

// ---------------------------------------------------------------------------
// Kernel 1: pack adjacency into PADDED ROW-MAJOR u64 bitmask rows.
// ---------------------------------------------------------------------------
__device__ __forceinline__ bool detect_byte_mode(const u32* a32) {
    int lane = threadIdx.x & 63;
    u32 or0 = 0, or1 = 0;
    #pragma unroll
    for (int k = 0; k < 16; ++k) {
        u32 v = a32[lane + k * 64];
        or0 |= v & 0x000000FFu;
        or1 |= v & 0x0000FF00u;
    }
    bool a0 = __any(or0 != 0);
    bool a1 = __any(or1 != 0);
    return a0 && a1;
}

__global__ __launch_bounds__(256) void build_adj(
        const u8* __restrict__ a8,
        const int* __restrict__ nn_,
        u64* __restrict__ adjW) {
    bool bytemode = detect_byte_mode((const u32*)a8);
    int t = blockIdx.x * blockDim.x + threadIdx.x;
    if (t >= ADJP_WORDS) return;
    int w = t % ROWW;
    int j = (t / ROWW) % Nn;
    int b = t / (ROWW * Nn);
    int nn = nn_[b];
    u64 bits = 0ull;
    if (w < WPN && j < nn) {
        int jbase = w * 64;
        int lim = nn - jbase; if (lim > 64) lim = 64;
        if (lim > 0) {
            long base = ((long)(b * Nn + j)) * Nn + jbase;
            if (bytemode) {
                const uint4* p = (const uint4*)(a8 + base);   // 64B
                #pragma unroll
                for (int v = 0; v < 4; ++v) {
                    uint4 x = p[v];
                    u32 n0 = ((x.x & 0x01010101u) * 0x01020408u) >> 24;
                    u32 n1 = ((x.y & 0x01010101u) * 0x01020408u) >> 24;
                    u32 n2 = ((x.z & 0x01010101u) * 0x01020408u) >> 24;
                    u32 n3 = ((x.w & 0x01010101u) * 0x01020408u) >> 24;
                    u64 nib = (u64)((n0 & 0xF) | ((n1 & 0xF) << 4) |
                                    ((n2 & 0xF) << 8) | ((n3 & 0xF) << 12));
                    bits |= nib << (v * 16);
                }
            } else {
                const uint4* p = (const uint4*)(((const u32*)a8) + base);  // 256B
                #pragma unroll
                for (int v = 0; v < 16; ++v) {
                    uint4 x = p[v];
                    u64 nib = (u64)((x.x != 0u) | ((x.y != 0u) << 1) |
                                    ((x.z != 0u) << 2) | ((x.w != 0u) << 3));
                    bits |= nib << (v * 4);
                }
            }
            if (lim < 64) bits &= (1ull << lim) - 1ull;
        }
    }
    adjW[t] = bits;
}

// ---------------------------------------------------------------------------
// Kernel 2: fused BFS + write (R0 structure, CH=16). 640 blocks x 256 threads
// (graph x 16-source chunk; wave wv owns sources wv*4..wv*4+3; 16 lanes per
// source = one DPP row). Frontier union + group counts via DPP row-rotate
// OR/ADD (VALU pipe) -- zero DS-pipe shuffles. No barrier after BFS: each
// wave reads only its own idx rows, so waves desync into the write phase.
// Staging via global_load_lds width-16 (direct global->LDS, linear dest).
// ---------------------------------------------------------------------------
__global__ __launch_bounds__(TPB) void bfs_write(
        const u64* __restrict__ adjW,
        const int* __restrict__ nn_,
        const float* __restrict__ emb,
        float4* __restrict__ out4) {
    int blk = blockIdx.x;
    int b = blk / NCHUNK, chunk = blk % NCHUNK;
    int t = threadIdx.x;
    int wv = t >> 6;
    int lane = t & 63;
    int s = lane >> 4;            // source-in-wave 0..3 (one DPP row)
    int k = lane & 15;            // segment 0..15 (20 nodes each)
    int r = wv * 4 + s;           // idx row 0..15

    __shared__ __align__(16) u64 adj_s[Nn * ROWW];    // 15360 B row-major
    __shared__ __align__(16) u8 idx_s[CH][IDXSTR];    // 5376 B
    __shared__ float emb_s[(MAXD + 2) * ESTR];        // 576 B

    if (t < 96) emb_s[(t >> 3) * ESTR + (t & 7)] = emb[t];

    // stage: 960 uint4 over 4 waves (last iteration is wave-aligned partial)
    {
        const uint4* g4 = (const uint4*)(adjW + (size_t)b * (Nn * ROWW));
        uint4* d4 = (uint4*)adj_s;
        #pragma unroll
        for (int it = 0; it < 4; ++it) {
            int i = it * TPB + t;
            if (i < 960) {
#if __has_builtin(__builtin_amdgcn_global_load_lds)
                __builtin_amdgcn_global_load_lds(
                    (const __attribute__((address_space(1))) void*)(g4 + i),
                    (__attribute__((address_space(3))) void*)(d4 + i),
                    16, 0, 0);
#else
                d4[i] = g4[i];
#endif
            }
        }
    }
    // zero idx tile (1344 u32)
    #pragma unroll
    for (int it = 0; it < 6; ++it) {
        int i = it * TPB + t;
        if (i < (CH * IDXSTR) / 4) ((u32*)idx_s)[i] = 0;
    }
    int nn = nn_[b];
    __syncthreads();   // drains vmcnt (global_load_lds) + lgkmcnt

    // ---- BFS: wave-independent from here ----
    u64 valid[WPN];
    #pragma unroll
    for (int w = 0; w < WPN; ++w) {
        int c = nn - w * 64;
        valid[w] = (c >= 64) ? ~0ull : ((c <= 0) ? 0ull : ((1ull << c) - 1ull));
    }
    int sg = chunk * CH + r;
    u64 cur[WPN] = {0,0,0,0,0}, vis[WPN] = {0,0,0,0,0};
    if (sg < nn) {
        cur[sg >> 6] = 1ull << (sg & 63);
        vis[sg >> 6] = cur[sg >> 6];
        if (k == 0) idx_s[r][sg] = 1;     // dist 0 -> emb idx 1
    }

    int base = 20 * k, w0 = base >> 6, sh = base & 63;
    u8* myseg = &idx_s[r][base];

    int level = 1;
    while (level <= Nn) {
        u64 unv[WPN];
        #pragma unroll
        for (int w = 0; w < WPN; ++w) unv[w] = valid[w] & ~vis[w];
        u32 segf, segu;
        {
            u64 f = cur[w0] >> sh, u = unv[w0] >> sh;
            if (sh > 44) { f |= cur[w0 + 1] << (64 - sh); u |= unv[w0 + 1] << (64 - sh); }
            segf = (u32)f & MASK20; segu = (u32)u & MASK20;
        }
        int fc = __popc(segf), uw = __popc(segu);
        fc = ror_add<ROW_ROR_1>(fc); fc = ror_add<ROW_ROR_2>(fc);
        fc = ror_add<ROW_ROR_4>(fc); fc = ror_add<ROW_ROR_8>(fc);
        uw = ror_add<ROW_ROR_1>(uw); uw = ror_add<ROW_ROR_2>(uw);
        uw = ror_add<ROW_ROR_4>(uw); uw = ror_add<ROW_ROR_8>(uw);
        if (!__any(fc != 0)) break;

        u64 nxt[WPN] = {0,0,0,0,0};
        if (fc > 0 && uw > 0) {
            if (fc <= uw) {
                // top-down: whole-row reads of my segment's frontier bits
                u32 m = segf;
                while (m) {
                    int j0 = base + __builtin_ctz(m); m &= m - 1;
                    int j1 = j0;
                    if (m) { j1 = base + __builtin_ctz(m); m &= m - 1; }
                    const u64* r0 = adj_s + j0 * ROWW;
                    const u64* r1 = adj_s + j1 * ROWW;
                    ulonglong2 a0 = *(const ulonglong2*)r0;
                    ulonglong2 a1 = *(const ulonglong2*)(r0 + 2);
                    u64 a4 = r0[4];
                    ulonglong2 b0 = *(const ulonglong2*)r1;
                    ulonglong2 b1 = *(const ulonglong2*)(r1 + 2);
                    u64 b4 = r1[4];
                    nxt[0] |= a0.x | b0.x; nxt[1] |= a0.y | b0.y;
                    nxt[2] |= a1.x | b1.x; nxt[3] |= a1.y | b1.y;
                    nxt[4] |= a4 | b4;
                }
            } else {
                // bottom-up over my unvisited segment
                u32 m = segu;
                while (m) {
                    int p0 = __builtin_ctz(m); m &= m - 1;
                    int p1 = p0; bool h = (m != 0u);
                    if (h) { p1 = __builtin_ctz(m); m &= m - 1; }
                    int j0 = base + p0, j1 = base + p1;
                    const u64* r0 = adj_s + j0 * ROWW;
                    const u64* r1 = adj_s + j1 * ROWW;
                    ulonglong2 a0 = *(const ulonglong2*)r0;
                    ulonglong2 a1 = *(const ulonglong2*)(r0 + 2);
                    u64 a4 = r0[4];
                    ulonglong2 b0 = *(const ulonglong2*)r1;
                    ulonglong2 b1 = *(const ulonglong2*)(r1 + 2);
                    u64 b4 = r1[4];
                    u64 t0 = (a0.x & cur[0]) | (a0.y & cur[1]) | (a1.x & cur[2]) |
                             (a1.y & cur[3]) | (a4 & cur[4]);
                    u64 t1 = (b0.x & cur[0]) | (b0.y & cur[1]) | (b1.x & cur[2]) |
                             (b1.y & cur[3]) | (b4 & cur[4]);
                    if (t0) nxt[j0 >> 6] |= 1ull << (j0 & 63);
                    if (h && t1) nxt[j1 >> 6] |= 1ull << (j1 & 63);
                }
            }
            // union across the source's 16 lanes: DPP row-rotate ORs (VALU)
            #pragma unroll
            for (int w = 0; w < WPN; ++w) {
                u64 v = nxt[w];
                v = ror_or64<ROW_ROR_1>(v);
                v = ror_or64<ROW_ROR_2>(v);
                v = ror_or64<ROW_ROR_4>(v);
                v = ror_or64<ROW_ROR_8>(v);
                nxt[w] = v & unv[w];
            }
            u64 any = nxt[0] | nxt[1] | nxt[2] | nxt[3] | nxt[4];
            if (any) {
                u8 val = (u8)((level < MAXD ? level : MAXD) + 1);
                u64 f = nxt[w0] >> sh;
                if (sh > 44) f |= nxt[w0 + 1] << (64 - sh);
                u32 segn = (u32)f & MASK20;
                while (segn) { int p = __builtin_ctz(segn); segn &= segn - 1; myseg[p] = val; }
                #pragma unroll
                for (int w = 0; w < WPN; ++w) vis[w] |= nxt[w];
            }
        }
        #pragma unroll
        for (int w = 0; w < WPN; ++w) cur[w] = nxt[w];
        ++level;
    }
    // NO barrier: each wave reads only its own idx rows below; the faster
    // wave starts its store stream immediately.

    // ---- write phase: my wave's 4 rows x 640 float4 ----
    float4* gout = out4 + (size_t)(b * Nn + chunk * CH) * (Nn * NH / 4);
    #pragma unroll
    for (int r2 = 0; r2 < 4; ++r2) {
        int rr = wv * 4 + r2;
        const u8* irow = idx_s[rr];
        float4* rowout = gout + rr * (Nn * NH / 4);
        #pragma unroll
        for (int i = 0; i < 10; ++i) {
            int f = i * 64 + lane;                // f4 index in row, 0..639
            int e = irow[f >> 1];
            const float* ep = emb_s + e * ESTR + ((f & 1) << 2);
            rowout[f] = *(const float4*)ep;
        }
    }
}

extern "C" void kernel_launch(void* const* d_in, const int* in_sizes, int n_in,
                              void* d_out, int out_size, void* d_ws, size_t ws_size,
                              hipStream_t stream) {
    const u8*    adj = (const u8*)d_in[0];
    const int*   nn  = (const int*)d_in[1];
    const float* emb = (const float*)d_in[2];

    u64* adjW = (u64*)d_ws;

    build_adj<<<(ADJP_WORDS + 255) / 256, 256, 0, stream>>>(adj, nn, adjW);
    bfs_write<<<Bn * NCHUNK, TPB, 0, stream>>>(adjW, nn, emb, (float4*)d_out);
}